// Round 1
// baseline (384.531 us; speedup 1.0000x reference)
//
#include <hip/hip_runtime.h>

// ---------- problem constants ----------
constexpr int T_SEQ = 2048;
constexpr int CDIM  = 768;
constexpr int HEADS = 12;
constexpr int DH    = 64;
constexpr int BATCH = 2;
constexpr int BH_TOT = BATCH * HEADS;   // 24
constexpr int NROWS  = BATCH * T_SEQ;   // 4096
constexpr float RMS_EPS = 1.1920929e-07f;  // np.finfo(float32).eps

typedef __attribute__((ext_vector_type(8))) short bf16x8;
typedef __attribute__((ext_vector_type(4))) float f32x4;
typedef __attribute__((ext_vector_type(4))) unsigned int u32x4;

__device__ __forceinline__ unsigned short f2bf(float f) {
    union { float f; unsigned int u; } v; v.f = f;
    unsigned int u = v.u;
    unsigned int r = (u + 0x7fffu + ((u >> 16) & 1u)) >> 16;  // RNE
    return (unsigned short)r;
}
__device__ __forceinline__ float b2f(unsigned short h) {
    union { unsigned int u; float f; } v; v.u = ((unsigned int)h) << 16;
    return v.f;
}

// ---------- prep: split x and W into bf16 hi/lo; build W^T splits ----------
__global__ __launch_bounds__(256) void prep_kernel(
    const float* __restrict__ x, const float* __restrict__ W,
    unsigned short* __restrict__ xh, unsigned short* __restrict__ xl,
    unsigned short* __restrict__ Wh, unsigned short* __restrict__ Wl,
    unsigned short* __restrict__ WTh, unsigned short* __restrict__ WTl)
{
    const size_t NC = (size_t)NROWS * CDIM;
    const size_t WSZ = (size_t)CDIM * CDIM;
    size_t stride = (size_t)gridDim.x * blockDim.x;
    for (size_t i = (size_t)blockIdx.x * blockDim.x + threadIdx.x; i < NC; i += stride) {
        float v = x[i];
        unsigned short h = f2bf(v);
        xh[i] = h; xl[i] = f2bf(v - b2f(h));
    }
    for (size_t i = (size_t)blockIdx.x * blockDim.x + threadIdx.x; i < WSZ; i += stride) {
        float v = W[i];
        unsigned short h = f2bf(v);
        unsigned short l = f2bf(v - b2f(h));
        Wh[i] = h; Wl[i] = l;
        size_t k = i / CDIM, c = i % CDIM;
        WTh[c * CDIM + k] = h; WTl[c * CDIM + k] = l;
    }
}

// ---------- NT split-bf16 MFMA GEMM: C[M,N] = A[M,K] * B[N,K]^T ----------
// 128x128 tile, BK=64, 256 threads (4 waves, each 64x64).
// acc += Ah*Bh + Ah*Bl + Al*Bh  (drops Al*Bl, ~2^-18 rel)
__global__ __launch_bounds__(256) void gemm_nt_split(
    const unsigned short* __restrict__ Ah, const unsigned short* __restrict__ Al,
    const unsigned short* __restrict__ Bh, const unsigned short* __restrict__ Bl,
    float* __restrict__ C, int M, int N, int K, int ldc)
{
    __shared__ unsigned short sAh[128 * 64], sAl[128 * 64], sBh[128 * 64], sBl[128 * 64];
    const int tid = threadIdx.x;
    const int lane = tid & 63;
    const int wv = tid >> 6;
    const int wr = wv >> 1, wc = wv & 1;
    const int M0 = blockIdx.y * 128, N0 = blockIdx.x * 128;

    f32x4 acc[4][4];
#pragma unroll
    for (int i = 0; i < 4; ++i)
#pragma unroll
        for (int j = 0; j < 4; ++j) acc[i][j] = (f32x4)0.0f;

    for (int k0 = 0; k0 < K; k0 += 64) {
        __syncthreads();
#pragma unroll
        for (int p = 0; p < 4; ++p) {
            int elem = (p * 256 + tid) * 8;         // ushort index in 128x64 tile
            int row = elem >> 6, col = elem & 63;
            size_t ga = (size_t)(M0 + row) * K + k0 + col;
            size_t gb = (size_t)(N0 + row) * K + k0 + col;
            *(u32x4*)&sAh[elem] = *(const u32x4*)&Ah[ga];
            *(u32x4*)&sAl[elem] = *(const u32x4*)&Al[ga];
            *(u32x4*)&sBh[elem] = *(const u32x4*)&Bh[gb];
            *(u32x4*)&sBl[elem] = *(const u32x4*)&Bl[gb];
        }
        __syncthreads();
#pragma unroll
        for (int ks = 0; ks < 2; ++ks) {
            const int ko = ks * 32 + (lane >> 4) * 8;
            bf16x8 ah[4], al[4], bh[4], bl[4];
#pragma unroll
            for (int mi = 0; mi < 4; ++mi) {
                int r = wr * 64 + mi * 16 + (lane & 15);
                ah[mi] = *(const bf16x8*)&sAh[r * 64 + ko];
                al[mi] = *(const bf16x8*)&sAl[r * 64 + ko];
            }
#pragma unroll
            for (int ni = 0; ni < 4; ++ni) {
                int r = wc * 64 + ni * 16 + (lane & 15);
                bh[ni] = *(const bf16x8*)&sBh[r * 64 + ko];
                bl[ni] = *(const bf16x8*)&sBl[r * 64 + ko];
            }
#pragma unroll
            for (int mi = 0; mi < 4; ++mi)
#pragma unroll
                for (int ni = 0; ni < 4; ++ni) {
                    acc[mi][ni] = __builtin_amdgcn_mfma_f32_16x16x32_bf16(ah[mi], bh[ni], acc[mi][ni], 0, 0, 0);
                    acc[mi][ni] = __builtin_amdgcn_mfma_f32_16x16x32_bf16(ah[mi], bl[ni], acc[mi][ni], 0, 0, 0);
                    acc[mi][ni] = __builtin_amdgcn_mfma_f32_16x16x32_bf16(al[mi], bh[ni], acc[mi][ni], 0, 0, 0);
                }
        }
    }
#pragma unroll
    for (int mi = 0; mi < 4; ++mi)
#pragma unroll
        for (int ni = 0; ni < 4; ++ni)
#pragma unroll
            for (int r = 0; r < 4; ++r) {
                int row = M0 + wr * 64 + mi * 16 + (lane >> 4) * 4 + r;
                int col = N0 + wc * 64 + ni * 16 + (lane & 15);
                C[(size_t)row * ldc + col] = acc[mi][ni][r];
            }
}

// ---------- fused RMSNorm + QKV write (split q,k; plain v) ----------
// one wave per (b,t,h) row of 64
__global__ __launch_bounds__(256) void rmsqkv_kernel(
    const float* __restrict__ wbuf,
    const float* __restrict__ g1, const float* __restrict__ g2, const float* __restrict__ g3,
    unsigned short* __restrict__ qh, unsigned short* __restrict__ ql,
    unsigned short* __restrict__ kh, unsigned short* __restrict__ kl,
    unsigned short* __restrict__ vb)
{
    const int lane = threadIdx.x & 63;
    const int wv = threadIdx.x >> 6;
    const int ridx = blockIdx.x * 4 + wv;          // 0 .. NROWS*HEADS-1
    const int bt = ridx / HEADS;
    const int h = ridx % HEADS;
    const int b = bt >> 11, t = bt & (T_SEQ - 1);

    float v = wbuf[(size_t)bt * CDIM + h * DH + lane];
    float ss = v * v;
#pragma unroll
    for (int m = 32; m; m >>= 1) ss += __shfl_xor(ss, m);
    float r = rsqrtf(ss * (1.0f / 64.0f) + RMS_EPS);
    float wn = v * r;

    size_t o = ((size_t)(b * HEADS + h) * T_SEQ + t) * DH + lane;
    float q = wn * g1[lane];
    unsigned short qhi = f2bf(q); qh[o] = qhi; ql[o] = f2bf(q - b2f(qhi));
    float k = wn * g2[lane];
    unsigned short khi = f2bf(k); kh[o] = khi; kl[o] = f2bf(k - b2f(khi));
    vb[o] = f2bf(wn * g3[lane]);
}

// ---------- transpose v [bh][t][f] -> vT [bh][f][t] ----------
__global__ __launch_bounds__(256) void vtrans_kernel(
    const unsigned short* __restrict__ vb, unsigned short* __restrict__ vT)
{
    __shared__ unsigned short tile[64][65];
    const int bh = blockIdx.y, t0 = blockIdx.x * 64;
    const int tid = threadIdx.x;
    const int c = tid & 63, r4 = tid >> 6;
#pragma unroll
    for (int i = 0; i < 16; ++i) {
        int rr = r4 + i * 4;
        tile[rr][c] = vb[((size_t)bh * T_SEQ + t0 + rr) * DH + c];
    }
    __syncthreads();
#pragma unroll
    for (int i = 0; i < 16; ++i) {
        int ff = r4 + i * 4;
        vT[((size_t)bh * DH + ff) * T_SEQ + t0 + c] = tile[c][ff];
    }
}

// ---------- scores: E = exp((Q K^T)/8), row/col sums via atomics ----------
// per (bh): 2048x2048, tile 128x128, K=64 (full). Split Q,K (3 MFMA combos).
__global__ __launch_bounds__(256) void scores_kernel(
    const unsigned short* __restrict__ qh, const unsigned short* __restrict__ ql,
    const unsigned short* __restrict__ kh, const unsigned short* __restrict__ kl,
    unsigned short* __restrict__ Ebuf, float* __restrict__ rowsum, float* __restrict__ colsum,
    int bh0)
{
    __shared__ unsigned short sAh[128 * 64], sAl[128 * 64], sBh[128 * 64], sBl[128 * 64];
    const int tid = threadIdx.x;
    const int lane = tid & 63;
    const int wv = tid >> 6;
    const int wr = wv >> 1, wc = wv & 1;
    const int ci = blockIdx.z;
    const int bh = bh0 + ci;
    const int I0 = blockIdx.y * 128, J0 = blockIdx.x * 128;

    size_t qbase = ((size_t)bh * T_SEQ + I0) * DH;
    size_t kbase = ((size_t)bh * T_SEQ + J0) * DH;
#pragma unroll
    for (int p = 0; p < 4; ++p) {
        int elem = (p * 256 + tid) * 8;            // tile is contiguous 16KB in global
        *(u32x4*)&sAh[elem] = *(const u32x4*)&qh[qbase + elem];
        *(u32x4*)&sAl[elem] = *(const u32x4*)&ql[qbase + elem];
        *(u32x4*)&sBh[elem] = *(const u32x4*)&kh[kbase + elem];
        *(u32x4*)&sBl[elem] = *(const u32x4*)&kl[kbase + elem];
    }
    __syncthreads();

    f32x4 acc[4][4];
#pragma unroll
    for (int i = 0; i < 4; ++i)
#pragma unroll
        for (int j = 0; j < 4; ++j) acc[i][j] = (f32x4)0.0f;

#pragma unroll
    for (int ks = 0; ks < 2; ++ks) {
        const int ko = ks * 32 + (lane >> 4) * 8;
        bf16x8 ah[4], al[4], bh_[4], bl[4];
#pragma unroll
        for (int mi = 0; mi < 4; ++mi) {
            int r = wr * 64 + mi * 16 + (lane & 15);
            ah[mi] = *(const bf16x8*)&sAh[r * 64 + ko];
            al[mi] = *(const bf16x8*)&sAl[r * 64 + ko];
        }
#pragma unroll
        for (int ni = 0; ni < 4; ++ni) {
            int r = wc * 64 + ni * 16 + (lane & 15);
            bh_[ni] = *(const bf16x8*)&sBh[r * 64 + ko];
            bl[ni] = *(const bf16x8*)&sBl[r * 64 + ko];
        }
#pragma unroll
        for (int mi = 0; mi < 4; ++mi)
#pragma unroll
            for (int ni = 0; ni < 4; ++ni) {
                acc[mi][ni] = __builtin_amdgcn_mfma_f32_16x16x32_bf16(ah[mi], bh_[ni], acc[mi][ni], 0, 0, 0);
                acc[mi][ni] = __builtin_amdgcn_mfma_f32_16x16x32_bf16(ah[mi], bl[ni], acc[mi][ni], 0, 0, 0);
                acc[mi][ni] = __builtin_amdgcn_mfma_f32_16x16x32_bf16(al[mi], bh_[ni], acc[mi][ni], 0, 0, 0);
            }
    }

    // E = exp(S/8) (safe: |S|<=8 since q,k are RMS-normalized); store bf16
#pragma unroll
    for (int mi = 0; mi < 4; ++mi)
#pragma unroll
        for (int ni = 0; ni < 4; ++ni)
#pragma unroll
            for (int r = 0; r < 4; ++r) {
                float e = __expf(acc[mi][ni][r] * 0.125f);
                acc[mi][ni][r] = e;
                int gi = I0 + wr * 64 + mi * 16 + (lane >> 4) * 4 + r;
                int gj = J0 + wc * 64 + ni * 16 + (lane & 15);
                Ebuf[((size_t)ci * T_SEQ + gi) * T_SEQ + gj] = f2bf(e);
            }
    // row partial sums (over this wave's 64 cols)
#pragma unroll
    for (int mi = 0; mi < 4; ++mi)
#pragma unroll
        for (int r = 0; r < 4; ++r) {
            float rp = acc[mi][0][r] + acc[mi][1][r] + acc[mi][2][r] + acc[mi][3][r];
            rp += __shfl_xor(rp, 1); rp += __shfl_xor(rp, 2);
            rp += __shfl_xor(rp, 4); rp += __shfl_xor(rp, 8);
            if ((lane & 15) == 0) {
                int gi = I0 + wr * 64 + mi * 16 + (lane >> 4) * 4 + r;
                atomicAdd(&rowsum[ci * T_SEQ + gi], rp);
            }
        }
    // col partial sums (over this wave's 64 rows)
#pragma unroll
    for (int ni = 0; ni < 4; ++ni) {
        float cp = 0.0f;
#pragma unroll
        for (int mi = 0; mi < 4; ++mi)
#pragma unroll
            for (int r = 0; r < 4; ++r) cp += acc[mi][ni][r];
        cp += __shfl_xor(cp, 16); cp += __shfl_xor(cp, 32);
        if ((lane >> 4) == 0) {
            int gj = J0 + wc * 64 + ni * 16 + (lane & 15);
            atomicAdd(&colsum[ci * T_SEQ + gj], cp);
        }
    }
}

// ---------- 1/x for row/col sums ----------
__global__ __launch_bounds__(256) void inv_kernel(
    const float* __restrict__ rs, const float* __restrict__ cs,
    float* __restrict__ ri, float* __restrict__ ci_, int n)
{
    int i = blockIdx.x * 256 + threadIdx.x;
    if (i < n) { ri[i] = 1.0f / rs[i]; ci_[i] = 1.0f / cs[i]; }
}

// ---------- apply bisoftmax + PV:  y[b,i,h,:] = sum_j a_ij * v_j ----------
// a_ij = E_ij * (1/rowsum_i + 1/colsum_j); tile: 128 i-rows x 64 f, K=2048 j.
__global__ __launch_bounds__(256) void pv_kernel(
    const unsigned short* __restrict__ Ebuf, const unsigned short* __restrict__ vT,
    const float* __restrict__ rowinv, const float* __restrict__ colinv,
    unsigned short* __restrict__ yh, unsigned short* __restrict__ yl, int bh0)
{
    const int tid = threadIdx.x;
    const int lane = tid & 63;
    const int wv = tid >> 6;
    const int ci = blockIdx.y;
    const int bh = bh0 + ci;
    const int b = bh / HEADS, h = bh % HEADS;
    const int I0 = blockIdx.x * 128 + wv * 32;
    const int kg = (lane >> 4) * 8;

    f32x4 acc[2][4];
#pragma unroll
    for (int i = 0; i < 2; ++i)
#pragma unroll
        for (int j = 0; j < 4; ++j) acc[i][j] = (f32x4)0.0f;

    float rinv[2];
#pragma unroll
    for (int mi = 0; mi < 2; ++mi)
        rinv[mi] = rowinv[ci * T_SEQ + I0 + mi * 16 + (lane & 15)];

    for (int jb = 0; jb < T_SEQ; jb += 32) {
        const int j8 = jb + kg;
        f32x4 cinv0 = *(const f32x4*)&colinv[ci * T_SEQ + j8];
        f32x4 cinv1 = *(const f32x4*)&colinv[ci * T_SEQ + j8 + 4];
        float ce[8];
#pragma unroll
        for (int q = 0; q < 4; ++q) { ce[q] = cinv0[q]; ce[4 + q] = cinv1[q]; }

        bf16x8 bfr[4];
#pragma unroll
        for (int ni = 0; ni < 4; ++ni)
            bfr[ni] = *(const bf16x8*)&vT[((size_t)bh * DH + ni * 16 + (lane & 15)) * T_SEQ + j8];

#pragma unroll
        for (int mi = 0; mi < 2; ++mi) {
            const int i = I0 + mi * 16 + (lane & 15);
            u32x4 ev = *(const u32x4*)&Ebuf[((size_t)ci * T_SEQ + i) * T_SEQ + j8];
            const float rv = rinv[mi];
            bf16x8 af;
#pragma unroll
            for (int q = 0; q < 4; ++q) {
                unsigned int u = ev[q];
                float e0 = b2f((unsigned short)(u & 0xffffu));
                float e1 = b2f((unsigned short)(u >> 16));
                af[2 * q]     = (short)f2bf(e0 * (rv + ce[2 * q]));
                af[2 * q + 1] = (short)f2bf(e1 * (rv + ce[2 * q + 1]));
            }
#pragma unroll
            for (int ni = 0; ni < 4; ++ni)
                acc[mi][ni] = __builtin_amdgcn_mfma_f32_16x16x32_bf16(af, bfr[ni], acc[mi][ni], 0, 0, 0);
        }
    }
    // write y (split bf16) at [b, i, h*64+f]
#pragma unroll
    for (int mi = 0; mi < 2; ++mi)
#pragma unroll
        for (int ni = 0; ni < 4; ++ni)
#pragma unroll
            for (int r = 0; r < 4; ++r) {
                int i = I0 + mi * 16 + (lane >> 4) * 4 + r;
                int col = h * DH + ni * 16 + (lane & 15);
                size_t o = ((size_t)b * T_SEQ + i) * CDIM + col;
                float vY = acc[mi][ni][r];
                unsigned short hi = f2bf(vY);
                yh[o] = hi; yl[o] = f2bf(vY - b2f(hi));
            }
}

// ---------- host ----------
extern "C" void kernel_launch(void* const* d_in, const int* in_sizes, int n_in,
                              void* d_out, int out_size, void* d_ws, size_t ws_size,
                              hipStream_t stream)
{
    const float* x  = (const float*)d_in[0];
    const float* W  = (const float*)d_in[1];
    const float* g1 = (const float*)d_in[2];
    const float* g2 = (const float*)d_in[3];
    const float* g3 = (const float*)d_in[4];
    float* out = (float*)d_out;

    char* p = (char*)d_ws;
    auto alloc = [&](size_t bytes) -> void* {
        void* r = (void*)p;
        p += (bytes + 255) & ~(size_t)255;
        return r;
    };
    const size_t NC  = (size_t)NROWS * CDIM;
    const size_t WSZ = (size_t)CDIM * CDIM;
    const size_t QSZ = (size_t)BH_TOT * T_SEQ * DH;

    unsigned short* xh  = (unsigned short*)alloc(NC * 2);
    unsigned short* xl  = (unsigned short*)alloc(NC * 2);
    unsigned short* Wh  = (unsigned short*)alloc(WSZ * 2);
    unsigned short* Wl  = (unsigned short*)alloc(WSZ * 2);
    unsigned short* WTh = (unsigned short*)alloc(WSZ * 2);
    unsigned short* WTl = (unsigned short*)alloc(WSZ * 2);
    float*          wbuf = (float*)alloc(NC * 4);
    unsigned short* qh_ = (unsigned short*)alloc(QSZ * 2);
    unsigned short* ql_ = (unsigned short*)alloc(QSZ * 2);
    unsigned short* kh_ = (unsigned short*)alloc(QSZ * 2);
    unsigned short* kl_ = (unsigned short*)alloc(QSZ * 2);
    unsigned short* vb  = (unsigned short*)alloc(QSZ * 2);
    unsigned short* vT  = (unsigned short*)alloc(QSZ * 2);
    unsigned short* yh  = (unsigned short*)alloc(NC * 2);
    unsigned short* yl  = (unsigned short*)alloc(NC * 2);
    float* rowsum = (float*)alloc((size_t)BH_TOT * T_SEQ * 4);
    float* colsum = (float*)alloc((size_t)BH_TOT * T_SEQ * 4);
    float* rowinv = (float*)alloc((size_t)BH_TOT * T_SEQ * 4);
    float* colinv = (float*)alloc((size_t)BH_TOT * T_SEQ * 4);

    size_t used = (size_t)(p - (char*)d_ws);
    const size_t esz = (size_t)T_SEQ * T_SEQ * 2;   // bf16 E per (b,h): 8 MB
    int CH = 1;
    if (ws_size > used) {
        size_t rem = ws_size - used;
        size_t c = rem / esz;
        CH = (c < 1) ? 1 : (c > (size_t)BH_TOT ? BH_TOT : (int)c);
    }
    unsigned short* Ebuf = (unsigned short*)alloc((size_t)CH * esz);

    prep_kernel<<<2048, 256, 0, stream>>>(x, W, xh, xl, Wh, Wl, WTh, WTl);
    gemm_nt_split<<<dim3(CDIM / 128, NROWS / 128), 256, 0, stream>>>(
        xh, xl, Wh, Wl, wbuf, NROWS, CDIM, CDIM, CDIM);
    rmsqkv_kernel<<<(NROWS * HEADS) / 4, 256, 0, stream>>>(
        wbuf, g1, g2, g3, qh_, ql_, kh_, kl_, vb);
    vtrans_kernel<<<dim3(T_SEQ / 64, BH_TOT), 256, 0, stream>>>(vb, vT);

    for (int c0 = 0; c0 < BH_TOT; c0 += CH) {
        int cc = (BH_TOT - c0 < CH) ? (BH_TOT - c0) : CH;
        hipMemsetAsync(rowsum, 0, (size_t)cc * T_SEQ * 4, stream);
        hipMemsetAsync(colsum, 0, (size_t)cc * T_SEQ * 4, stream);
        scores_kernel<<<dim3(T_SEQ / 128, T_SEQ / 128, cc), 256, 0, stream>>>(
            qh_, ql_, kh_, kl_, Ebuf, rowsum, colsum, c0);
        int n = cc * T_SEQ;
        inv_kernel<<<(n + 255) / 256, 256, 0, stream>>>(rowsum, colsum, rowinv, colinv, n);
        pv_kernel<<<dim3(T_SEQ / 128, cc), 256, 0, stream>>>(
            Ebuf, vT, rowinv, colinv, yh, yl, c0);
    }

    gemm_nt_split<<<dim3(CDIM / 128, NROWS / 128), 256, 0, stream>>>(
        yh, yl, WTh, WTl, out, NROWS, CDIM, CDIM, CDIM);
}

// Round 2
// 291.686 us; speedup vs baseline: 1.3183x; 1.3183x over previous
//
#include <hip/hip_runtime.h>

// ---------- problem constants ----------
constexpr int T_SEQ = 2048;
constexpr int CDIM  = 768;
constexpr int HEADS = 12;
constexpr int DH    = 64;
constexpr int BATCH = 2;
constexpr int BH_TOT = BATCH * HEADS;   // 24
constexpr int NROWS  = BATCH * T_SEQ;   // 4096
constexpr float RMS_EPS = 1.1920929e-07f;  // np.finfo(float32).eps

typedef __attribute__((ext_vector_type(8))) short bf16x8;
typedef __attribute__((ext_vector_type(4))) float f32x4;
typedef __attribute__((ext_vector_type(4))) unsigned int u32x4;

__device__ __forceinline__ unsigned short f2bf(float f) {
    union { float f; unsigned int u; } v; v.f = f;
    unsigned int u = v.u;
    unsigned int r = (u + 0x7fffu + ((u >> 16) & 1u)) >> 16;  // RNE
    return (unsigned short)r;
}
__device__ __forceinline__ float b2f(unsigned short h) {
    union { unsigned int u; float f; } v; v.u = ((unsigned int)h) << 16;
    return v.f;
}

// ---------- prep: split x and W into bf16 hi/lo; build W^T splits ----------
__global__ __launch_bounds__(256) void prep_kernel(
    const float* __restrict__ x, const float* __restrict__ W,
    unsigned short* __restrict__ xh, unsigned short* __restrict__ xl,
    unsigned short* __restrict__ Wh, unsigned short* __restrict__ Wl,
    unsigned short* __restrict__ WTh, unsigned short* __restrict__ WTl)
{
    const size_t NC = (size_t)NROWS * CDIM;
    const size_t WSZ = (size_t)CDIM * CDIM;
    size_t stride = (size_t)gridDim.x * blockDim.x;
    for (size_t i = (size_t)blockIdx.x * blockDim.x + threadIdx.x; i < NC; i += stride) {
        float v = x[i];
        unsigned short h = f2bf(v);
        xh[i] = h; xl[i] = f2bf(v - b2f(h));
    }
    for (size_t i = (size_t)blockIdx.x * blockDim.x + threadIdx.x; i < WSZ; i += stride) {
        float v = W[i];
        unsigned short h = f2bf(v);
        unsigned short l = f2bf(v - b2f(h));
        Wh[i] = h; Wl[i] = l;
        size_t k = i / CDIM, c = i % CDIM;
        WTh[c * CDIM + k] = h; WTl[c * CDIM + k] = l;
    }
}

// ---------- NT split-bf16 MFMA GEMM: C[M,N] = A[M,K] * B[N,K]^T ----------
__global__ __launch_bounds__(256) void gemm_nt_split(
    const unsigned short* __restrict__ Ah, const unsigned short* __restrict__ Al,
    const unsigned short* __restrict__ Bh, const unsigned short* __restrict__ Bl,
    float* __restrict__ C, int M, int N, int K, int ldc)
{
    __shared__ unsigned short sAh[128 * 64], sAl[128 * 64], sBh[128 * 64], sBl[128 * 64];
    const int tid = threadIdx.x;
    const int lane = tid & 63;
    const int wv = tid >> 6;
    const int wr = wv >> 1, wc = wv & 1;
    const int M0 = blockIdx.y * 128, N0 = blockIdx.x * 128;

    f32x4 acc[4][4];
#pragma unroll
    for (int i = 0; i < 4; ++i)
#pragma unroll
        for (int j = 0; j < 4; ++j) acc[i][j] = (f32x4)0.0f;

    for (int k0 = 0; k0 < K; k0 += 64) {
        __syncthreads();
#pragma unroll
        for (int p = 0; p < 4; ++p) {
            int elem = (p * 256 + tid) * 8;         // ushort index in 128x64 tile
            int row = elem >> 6;
            int off = (elem * 2) ^ ((row & 7) << 4);   // XOR-swizzle vs bank conflicts
            size_t ga = (size_t)(M0 + row) * K + k0 + (elem & 63);
            size_t gb = (size_t)(N0 + row) * K + k0 + (elem & 63);
            *(u32x4*)((char*)sAh + off) = *(const u32x4*)&Ah[ga];
            *(u32x4*)((char*)sAl + off) = *(const u32x4*)&Al[ga];
            *(u32x4*)((char*)sBh + off) = *(const u32x4*)&Bh[gb];
            *(u32x4*)((char*)sBl + off) = *(const u32x4*)&Bl[gb];
        }
        __syncthreads();
#pragma unroll
        for (int ks = 0; ks < 2; ++ks) {
            const int ko = ks * 32 + (lane >> 4) * 8;
            bf16x8 ah[4], al[4], bh[4], bl[4];
#pragma unroll
            for (int mi = 0; mi < 4; ++mi) {
                int r = wr * 64 + mi * 16 + (lane & 15);
                int off = (r * 128 + ko * 2) ^ ((r & 7) << 4);
                ah[mi] = *(const bf16x8*)((char*)sAh + off);
                al[mi] = *(const bf16x8*)((char*)sAl + off);
            }
#pragma unroll
            for (int ni = 0; ni < 4; ++ni) {
                int r = wc * 64 + ni * 16 + (lane & 15);
                int off = (r * 128 + ko * 2) ^ ((r & 7) << 4);
                bh[ni] = *(const bf16x8*)((char*)sBh + off);
                bl[ni] = *(const bf16x8*)((char*)sBl + off);
            }
#pragma unroll
            for (int mi = 0; mi < 4; ++mi)
#pragma unroll
                for (int ni = 0; ni < 4; ++ni) {
                    acc[mi][ni] = __builtin_amdgcn_mfma_f32_16x16x32_bf16(ah[mi], bh[ni], acc[mi][ni], 0, 0, 0);
                    acc[mi][ni] = __builtin_amdgcn_mfma_f32_16x16x32_bf16(ah[mi], bl[ni], acc[mi][ni], 0, 0, 0);
                    acc[mi][ni] = __builtin_amdgcn_mfma_f32_16x16x32_bf16(al[mi], bh[ni], acc[mi][ni], 0, 0, 0);
                }
        }
    }
#pragma unroll
    for (int mi = 0; mi < 4; ++mi)
#pragma unroll
        for (int ni = 0; ni < 4; ++ni)
#pragma unroll
            for (int r = 0; r < 4; ++r) {
                int row = M0 + wr * 64 + mi * 16 + (lane >> 4) * 4 + r;
                int col = N0 + wc * 64 + ni * 16 + (lane & 15);
                C[(size_t)row * ldc + col] = acc[mi][ni][r];
            }
}

// ---------- fused RMSNorm + QKV write (plain bf16 q,k,v) ----------
__global__ __launch_bounds__(256) void rmsqkv_kernel(
    const float* __restrict__ wbuf,
    const float* __restrict__ g1, const float* __restrict__ g2, const float* __restrict__ g3,
    unsigned short* __restrict__ qb, unsigned short* __restrict__ kb,
    unsigned short* __restrict__ vb)
{
    const int lane = threadIdx.x & 63;
    const int wv = threadIdx.x >> 6;
    const int ridx = blockIdx.x * 4 + wv;          // 0 .. NROWS*HEADS-1
    const int bt = ridx / HEADS;
    const int h = ridx % HEADS;
    const int b = bt >> 11, t = bt & (T_SEQ - 1);

    float v = wbuf[(size_t)bt * CDIM + h * DH + lane];
    float ss = v * v;
#pragma unroll
    for (int m = 32; m; m >>= 1) ss += __shfl_xor(ss, m);
    float r = rsqrtf(ss * (1.0f / 64.0f) + RMS_EPS);
    float wn = v * r;

    size_t o = ((size_t)(b * HEADS + h) * T_SEQ + t) * DH + lane;
    qb[o] = f2bf(wn * g1[lane]);
    kb[o] = f2bf(wn * g2[lane]);
    vb[o] = f2bf(wn * g3[lane]);
}

// ---------- transpose v [bh][t][f] -> vT [bh][f][t] ----------
__global__ __launch_bounds__(256) void vtrans_kernel(
    const unsigned short* __restrict__ vb, unsigned short* __restrict__ vT)
{
    __shared__ unsigned short tile[64][65];
    const int bh = blockIdx.y, t0 = blockIdx.x * 64;
    const int tid = threadIdx.x;
    const int c = tid & 63, r4 = tid >> 6;
#pragma unroll
    for (int i = 0; i < 16; ++i) {
        int rr = r4 + i * 4;
        tile[rr][c] = vb[((size_t)bh * T_SEQ + t0 + rr) * DH + c];
    }
    __syncthreads();
#pragma unroll
    for (int i = 0; i < 16; ++i) {
        int ff = r4 + i * 4;
        vT[((size_t)bh * DH + ff) * T_SEQ + t0 + c] = tile[c][ff];
    }
}

// ---------- pass 1: row/col sums of E = exp(QK^T/8); NO E materialization ----
__global__ __launch_bounds__(256) void sums_kernel(
    const unsigned short* __restrict__ qb, const unsigned short* __restrict__ kb,
    float* __restrict__ rowsum, float* __restrict__ colsum)
{
    __shared__ unsigned short sQ[128 * 64], sK[128 * 64];
    const int tid = threadIdx.x;
    const int lane = tid & 63;
    const int wv = tid >> 6;
    const int wr = wv >> 1, wc = wv & 1;
    const int bh = blockIdx.z;
    const int I0 = blockIdx.y * 128, J0 = blockIdx.x * 128;

    size_t qbase = ((size_t)bh * T_SEQ + I0) * DH;
    size_t kbase = ((size_t)bh * T_SEQ + J0) * DH;
#pragma unroll
    for (int p = 0; p < 4; ++p) {
        int elem = (p * 256 + tid) * 8;
        int row = elem >> 6;
        int off = (elem * 2) ^ ((row & 7) << 4);
        *(u32x4*)((char*)sQ + off) = *(const u32x4*)&qb[qbase + elem];
        *(u32x4*)((char*)sK + off) = *(const u32x4*)&kb[kbase + elem];
    }
    __syncthreads();

    f32x4 acc[4][4];
#pragma unroll
    for (int i = 0; i < 4; ++i)
#pragma unroll
        for (int j = 0; j < 4; ++j) acc[i][j] = (f32x4)0.0f;

#pragma unroll
    for (int ks = 0; ks < 2; ++ks) {
        const int ko = ks * 32 + (lane >> 4) * 8;
        bf16x8 a[4], b[4];
#pragma unroll
        for (int mi = 0; mi < 4; ++mi) {
            int r = wr * 64 + mi * 16 + (lane & 15);
            a[mi] = *(const bf16x8*)((char*)sQ + ((r * 128 + ko * 2) ^ ((r & 7) << 4)));
        }
#pragma unroll
        for (int ni = 0; ni < 4; ++ni) {
            int r = wc * 64 + ni * 16 + (lane & 15);
            b[ni] = *(const bf16x8*)((char*)sK + ((r * 128 + ko * 2) ^ ((r & 7) << 4)));
        }
#pragma unroll
        for (int mi = 0; mi < 4; ++mi)
#pragma unroll
            for (int ni = 0; ni < 4; ++ni)
                acc[mi][ni] = __builtin_amdgcn_mfma_f32_16x16x32_bf16(a[mi], b[ni], acc[mi][ni], 0, 0, 0);
    }

    // E = exp(S/8) (|S|<=64 since ||q||=||k||=8) -> row/col partial sums
#pragma unroll
    for (int mi = 0; mi < 4; ++mi)
#pragma unroll
        for (int ni = 0; ni < 4; ++ni)
#pragma unroll
            for (int r = 0; r < 4; ++r)
                acc[mi][ni][r] = __expf(acc[mi][ni][r] * 0.125f);

#pragma unroll
    for (int mi = 0; mi < 4; ++mi)
#pragma unroll
        for (int r = 0; r < 4; ++r) {
            float rp = acc[mi][0][r] + acc[mi][1][r] + acc[mi][2][r] + acc[mi][3][r];
            rp += __shfl_xor(rp, 1); rp += __shfl_xor(rp, 2);
            rp += __shfl_xor(rp, 4); rp += __shfl_xor(rp, 8);
            if ((lane & 15) == 0) {
                int gi = I0 + wr * 64 + mi * 16 + (lane >> 4) * 4 + r;
                atomicAdd(&rowsum[bh * T_SEQ + gi], rp);
            }
        }
#pragma unroll
    for (int ni = 0; ni < 4; ++ni) {
        float cp = 0.0f;
#pragma unroll
        for (int mi = 0; mi < 4; ++mi)
#pragma unroll
            for (int r = 0; r < 4; ++r) cp += acc[mi][ni][r];
        cp += __shfl_xor(cp, 16); cp += __shfl_xor(cp, 32);
        if ((lane >> 4) == 0) {
            int gj = J0 + wc * 64 + ni * 16 + (lane & 15);
            atomicAdd(&colsum[bh * T_SEQ + gj], cp);
        }
    }
}

// ---------- 1/x for row/col sums ----------
__global__ __launch_bounds__(256) void inv_kernel(
    const float* __restrict__ rs, const float* __restrict__ cs,
    float* __restrict__ ri, float* __restrict__ ci_, int n)
{
    int i = blockIdx.x * 256 + threadIdx.x;
    if (i < n) { ri[i] = 1.0f / rs[i]; ci_[i] = 1.0f / cs[i]; }
}

// ---------- pass 2: recompute S tile-wise, a = E*(rinv+cinv), y += a*V ------
// grid: (T/64 i-tiles, BH). block 256 = 4 waves. j-loop in 128-tiles.
__global__ __launch_bounds__(256) void fused_pv_kernel(
    const unsigned short* __restrict__ qb, const unsigned short* __restrict__ kb,
    const unsigned short* __restrict__ vT,
    const float* __restrict__ rowinv, const float* __restrict__ colinv,
    unsigned short* __restrict__ yh, unsigned short* __restrict__ yl)
{
    __shared__ unsigned short sQ[64 * 64];     // 8 KB
    __shared__ unsigned short sK[128 * 64];    // 16 KB
    __shared__ unsigned short sP[64 * 128];    // 16 KB
    __shared__ float srinv[64];

    const int tid = threadIdx.x;
    const int lane = tid & 63;
    const int wv = tid >> 6;
    const int wr = wv >> 1, wc = wv & 1;
    const int bh = blockIdx.y;
    const int b = bh / HEADS, h = bh % HEADS;
    const int I0 = blockIdx.x * 64;

    // stage Q tile (64x64) with XOR swizzle
    size_t qbase = ((size_t)bh * T_SEQ + I0) * DH;
#pragma unroll
    for (int p = 0; p < 2; ++p) {
        int elem = (p * 256 + tid) * 8;
        int row = elem >> 6;
        int off = (elem * 2) ^ ((row & 7) << 4);
        *(u32x4*)((char*)sQ + off) = *(const u32x4*)&qb[qbase + elem];
    }
    if (tid < 64) srinv[tid] = rowinv[bh * T_SEQ + I0 + tid];

    f32x4 accy[4];
#pragma unroll
    for (int i = 0; i < 4; ++i) accy[i] = (f32x4)0.0f;

    for (int jb = 0; jb < T_SEQ; jb += 128) {
        __syncthreads();   // prev PV done with sP; prev QK^T done with sK; (1st: sQ ready)
        size_t kbase = ((size_t)bh * T_SEQ + jb) * DH;
#pragma unroll
        for (int p = 0; p < 4; ++p) {
            int elem = (p * 256 + tid) * 8;
            int row = elem >> 6;
            int off = (elem * 2) ^ ((row & 7) << 4);
            *(u32x4*)((char*)sK + off) = *(const u32x4*)&kb[kbase + elem];
        }
        __syncthreads();

        // QK^T: S tile 64x128; wave (wr,wc) does 32 rows x 64 cols
        f32x4 accs[2][4];
#pragma unroll
        for (int i = 0; i < 2; ++i)
#pragma unroll
            for (int j = 0; j < 4; ++j) accs[i][j] = (f32x4)0.0f;
#pragma unroll
        for (int ks = 0; ks < 2; ++ks) {
            const int ko = ks * 32 + (lane >> 4) * 8;
            bf16x8 a[2], bfr[4];
#pragma unroll
            for (int mi = 0; mi < 2; ++mi) {
                int r = wr * 32 + mi * 16 + (lane & 15);
                a[mi] = *(const bf16x8*)((char*)sQ + ((r * 128 + ko * 2) ^ ((r & 7) << 4)));
            }
#pragma unroll
            for (int ni = 0; ni < 4; ++ni) {
                int r = wc * 64 + ni * 16 + (lane & 15);
                bfr[ni] = *(const bf16x8*)((char*)sK + ((r * 128 + ko * 2) ^ ((r & 7) << 4)));
            }
#pragma unroll
            for (int mi = 0; mi < 2; ++mi)
#pragma unroll
                for (int ni = 0; ni < 4; ++ni)
                    accs[mi][ni] = __builtin_amdgcn_mfma_f32_16x16x32_bf16(a[mi], bfr[ni], accs[mi][ni], 0, 0, 0);
        }

        // a = exp(S/8)*(rinv + cinv) -> bf16 -> sP (swizzled)
        float cv[4];
#pragma unroll
        for (int ni = 0; ni < 4; ++ni)
            cv[ni] = colinv[bh * T_SEQ + jb + wc * 64 + ni * 16 + (lane & 15)];
#pragma unroll
        for (int mi = 0; mi < 2; ++mi)
#pragma unroll
            for (int r = 0; r < 4; ++r) {
                int row = wr * 32 + mi * 16 + (lane >> 4) * 4 + r;
                float rv = srinv[row];
#pragma unroll
                for (int ni = 0; ni < 4; ++ni) {
                    float e = __expf(accs[mi][ni][r] * 0.125f);
                    int col = wc * 64 + ni * 16 + (lane & 15);
                    int off = (row * 256 + col * 2) ^ ((row & 7) << 4);
                    *(unsigned short*)((char*)sP + off) = f2bf(e * (rv + cv[ni]));
                }
            }
        __syncthreads();

        // PV: y[64x64] += P[64x128] * V[128x64]; wave wv does 16 rows
#pragma unroll
        for (int ks = 0; ks < 4; ++ks) {
            const int ko = ks * 32 + (lane >> 4) * 8;
            int arow = wv * 16 + (lane & 15);
            bf16x8 pa = *(const bf16x8*)((char*)sP + ((arow * 256 + ko * 2) ^ ((arow & 7) << 4)));
#pragma unroll
            for (int ni = 0; ni < 4; ++ni) {
                bf16x8 vb_ = *(const bf16x8*)&vT[((size_t)bh * DH + ni * 16 + (lane & 15)) * T_SEQ + jb + ko];
                accy[ni] = __builtin_amdgcn_mfma_f32_16x16x32_bf16(pa, vb_, accy[ni], 0, 0, 0);
            }
        }
    }

    // write y (split bf16) at [b, i, h*64+f]
#pragma unroll
    for (int ni = 0; ni < 4; ++ni)
#pragma unroll
        for (int r = 0; r < 4; ++r) {
            int i = I0 + wv * 16 + (lane >> 4) * 4 + r;
            int col = h * DH + ni * 16 + (lane & 15);
            size_t o = ((size_t)b * T_SEQ + i) * CDIM + col;
            float vY = accy[ni][r];
            unsigned short hi = f2bf(vY);
            yh[o] = hi; yl[o] = f2bf(vY - b2f(hi));
        }
}

// ---------- host ----------
extern "C" void kernel_launch(void* const* d_in, const int* in_sizes, int n_in,
                              void* d_out, int out_size, void* d_ws, size_t ws_size,
                              hipStream_t stream)
{
    const float* x  = (const float*)d_in[0];
    const float* W  = (const float*)d_in[1];
    const float* g1 = (const float*)d_in[2];
    const float* g2 = (const float*)d_in[3];
    const float* g3 = (const float*)d_in[4];
    float* out = (float*)d_out;

    char* p = (char*)d_ws;
    auto alloc = [&](size_t bytes) -> void* {
        void* r = (void*)p;
        p += (bytes + 255) & ~(size_t)255;
        return r;
    };
    const size_t NC  = (size_t)NROWS * CDIM;
    const size_t WSZ = (size_t)CDIM * CDIM;
    const size_t QSZ = (size_t)BH_TOT * T_SEQ * DH;

    unsigned short* xh  = (unsigned short*)alloc(NC * 2);
    unsigned short* xl  = (unsigned short*)alloc(NC * 2);
    unsigned short* Wh  = (unsigned short*)alloc(WSZ * 2);
    unsigned short* Wl  = (unsigned short*)alloc(WSZ * 2);
    unsigned short* WTh = (unsigned short*)alloc(WSZ * 2);
    unsigned short* WTl = (unsigned short*)alloc(WSZ * 2);
    float*          wbuf = (float*)alloc(NC * 4);
    unsigned short* qb  = (unsigned short*)alloc(QSZ * 2);
    unsigned short* kb  = (unsigned short*)alloc(QSZ * 2);
    unsigned short* vb  = (unsigned short*)alloc(QSZ * 2);
    unsigned short* vT  = (unsigned short*)alloc(QSZ * 2);
    unsigned short* yh  = (unsigned short*)alloc(NC * 2);
    unsigned short* yl  = (unsigned short*)alloc(NC * 2);
    float* rowsum = (float*)alloc((size_t)BH_TOT * T_SEQ * 4);
    float* colsum = (float*)alloc((size_t)BH_TOT * T_SEQ * 4);
    float* rowinv = (float*)alloc((size_t)BH_TOT * T_SEQ * 4);
    float* colinv = (float*)alloc((size_t)BH_TOT * T_SEQ * 4);

    prep_kernel<<<2048, 256, 0, stream>>>(x, W, xh, xl, Wh, Wl, WTh, WTl);
    gemm_nt_split<<<dim3(CDIM / 128, NROWS / 128), 256, 0, stream>>>(
        xh, xl, Wh, Wl, wbuf, NROWS, CDIM, CDIM, CDIM);
    rmsqkv_kernel<<<(NROWS * HEADS) / 4, 256, 0, stream>>>(
        wbuf, g1, g2, g3, qb, kb, vb);
    vtrans_kernel<<<dim3(T_SEQ / 64, BH_TOT), 256, 0, stream>>>(vb, vT);

    hipMemsetAsync(rowsum, 0, (size_t)BH_TOT * T_SEQ * 4, stream);
    hipMemsetAsync(colsum, 0, (size_t)BH_TOT * T_SEQ * 4, stream);
    sums_kernel<<<dim3(T_SEQ / 128, T_SEQ / 128, BH_TOT), 256, 0, stream>>>(
        qb, kb, rowsum, colsum);
    int n = BH_TOT * T_SEQ;
    inv_kernel<<<(n + 255) / 256, 256, 0, stream>>>(rowsum, colsum, rowinv, colinv, n);
    fused_pv_kernel<<<dim3(T_SEQ / 64, BH_TOT), 256, 0, stream>>>(
        qb, kb, vT, rowinv, colinv, yh, yl);

    gemm_nt_split<<<dim3(CDIM / 128, NROWS / 128), 256, 0, stream>>>(
        yh, yl, WTh, WTl, out, NROWS, CDIM, CDIM, CDIM);
}